// Round 12
// baseline (343.309 us; speedup 1.0000x reference)
//
#include <hip/hip_runtime.h>
#include <stdint.h>

typedef __bf16 bf16;
typedef __bf16 bf16x8 __attribute__((ext_vector_type(8)));
typedef float f32x4 __attribute__((ext_vector_type(4)));

__device__ __forceinline__ float bfbits2f(uint32_t lo16) {
    uint32_t b = lo16 << 16;
    float f;
    __builtin_memcpy(&f, &b, 4);
    return f;
}

__device__ __forceinline__ uint32_t pack2bf(float a, float b) {
    uint32_t lo = __builtin_bit_cast(unsigned short, (bf16)a);
    uint32_t hi = __builtin_bit_cast(unsigned short, (bf16)b);
    return lo | (hi << 16);
}

__device__ __forceinline__ void gload_lds16(const void* g, void* l) {
    __builtin_amdgcn_global_load_lds((const __attribute__((address_space(1))) void*)g,
                                     (__attribute__((address_space(3))) void*)l, 16, 0, 0);
}

// ---- prep: W1T[h][f]=W1[f][h];  WcatT2[o][r*128+c]=weight[r][c][o],
// WcatT2[o][R*128+c]=root[c][o];  tail computes qc:
// qc[i]=sum_j W2[i][j]*Wo[j], qc[128]=b2.Wo+bo
__global__ void k_prep(const float* __restrict__ W1, const float* __restrict__ weight,
                       const float* __restrict__ root, const float* __restrict__ W2,
                       const float* __restrict__ b2, const float* __restrict__ Wo,
                       const float* __restrict__ bo, bf16* __restrict__ W1T,
                       bf16* __restrict__ WcatT2, float* __restrict__ qc, int R, int ldt) {
    int total = 16384 * (R + 2);
    for (int i = blockIdx.x * blockDim.x + threadIdx.x; i < total + 129; i += gridDim.x * blockDim.x) {
        if (i < 16384) {
            int f = i >> 7, h = i & 127;
            W1T[h * 128 + f] = (bf16)W1[f * 128 + h];
        } else if (i < total) {
            int j = i - 16384;
            int r = j >> 14, rem = j & 16383, c = rem >> 7, o = rem & 127;
            float v = (r < R) ? weight[(size_t)(r * 128 + c) * 128 + o] : root[c * 128 + o];
            WcatT2[(size_t)o * ldt + r * 128 + c] = (bf16)v;
        } else {
            int t = i - total;
            if (t < 128) {
                float s = 0.f;
                for (int j = 0; j < 128; j++) s += W2[t * 128 + j] * Wo[j];
                qc[t] = s;
            } else {
                float c = bo[0];
                for (int j = 0; j < 128; j++) c += b2[j] * Wo[j];
                qc[128] = c;
            }
        }
    }
}

// ---- CSR build over segments seg = dst*R + etype (dst-major: node's edges
// contiguous AND grouped by etype within the node -> agg2 run-accumulation) ----
__global__ void k_hist(const int* __restrict__ dst, const int* __restrict__ etype,
                       int* __restrict__ cnt, int E, int R) {
    for (int e = blockIdx.x * blockDim.x + threadIdx.x; e < E; e += gridDim.x * blockDim.x)
        atomicAdd(&cnt[dst[e] * R + etype[e]], 1);
}

__global__ __launch_bounds__(256) void k_scan_blk(const int* __restrict__ cnt, int* __restrict__ bsum, int M) {
    int i = blockIdx.x * 256 + threadIdx.x;
    int v = (i < M) ? cnt[i] : 0;
#pragma unroll
    for (int d = 1; d < 64; d <<= 1) v += __shfl_xor(v, d);
    __shared__ int ws[4];
    if ((threadIdx.x & 63) == 0) ws[threadIdx.x >> 6] = v;
    __syncthreads();
    if (threadIdx.x == 0) bsum[blockIdx.x] = ws[0] + ws[1] + ws[2] + ws[3];
}

// looped single-block exclusive scan over nb block sums (nb up to 2048)
__global__ __launch_bounds__(256) void k_scan_top(int* __restrict__ bsum, int nb) {
    __shared__ int s[256];
    __shared__ int carry;
    int t = threadIdx.x;
    if (t == 0) carry = 0;
    __syncthreads();
    for (int base = 0; base < nb; base += 256) {
        int i = base + t;
        int v = (i < nb) ? bsum[i] : 0;
        s[t] = v;
        __syncthreads();
#pragma unroll
        for (int d = 1; d < 256; d <<= 1) {
            int u = (t >= d) ? s[t - d] : 0;
            __syncthreads();
            s[t] += u;
            __syncthreads();
        }
        int excl = carry + s[t] - v;
        int tot = s[255];
        __syncthreads();
        if (i < nb) bsum[i] = excl;
        if (t == 0) carry += tot;
        __syncthreads();
    }
}

__global__ __launch_bounds__(256) void k_scan_apply(const int* __restrict__ cnt, const int* __restrict__ bsum,
                                                    int* __restrict__ row_off, int* __restrict__ cursor, int M) {
    int b = blockIdx.x, t = threadIdx.x;
    int i = b * 256 + t;
    int v = (i < M) ? cnt[i] : 0;
    int lane = t & 63, wid = t >> 6;
    int incl = v;
#pragma unroll
    for (int d = 1; d < 64; d <<= 1) {
        int u = __shfl_up(incl, d);
        if (lane >= d) incl += u;
    }
    __shared__ int ws[4];
    if (lane == 63) ws[wid] = incl;
    __syncthreads();
    int woff = 0;
    for (int wj = 0; wj < 4; wj++)
        if (wj < wid) woff += ws[wj];
    int excl = bsum[b] + woff + incl - v;
    if (i < M) {
        row_off[i] = excl;
        cursor[i] = excl;
        if (i == M - 1) row_off[M] = excl + v;
    }
}

// XCD-partitioned CSR fill on seg ranges. payload = (etype<<16)|src.
__global__ void k_fill(const int* __restrict__ src, const int* __restrict__ dst,
                       const int* __restrict__ etype, int* __restrict__ cursor,
                       int* __restrict__ csr, int E, int R, int pbase) {
    int p = blockIdx.x & 7;
    int bg = blockIdx.x >> 3;
    int nchunk = gridDim.x >> 3;
    int chunk = (E + nchunk - 1) / nchunk;
    int beg = bg * chunk, end = min(beg + chunk, E);
    int lo = p * pbase, hi = lo + pbase;
    for (int e = beg + (int)threadIdx.x; e < end; e += blockDim.x) {
        int et = etype[e];
        int seg = dst[e] * R + et;
        if (seg >= lo && seg < hi) {
            int pos = atomicAdd(&cursor[seg], 1);
            csr[pos] = (et << 16) | src[e];
        }
    }
}

// ---- GEMM (layer 0): C[M x 128] = A_f32[M x 128] * B[128 x 128] (+bias), bf16 out
__global__ __launch_bounds__(256) void k_gemm0(const float* __restrict__ A, const bf16* __restrict__ BT,
                                               const float* __restrict__ bias, bf16* __restrict__ C, int M) {
    __shared__ bf16 sA[128 * 128];
    __shared__ bf16 sB[128 * 128];
    int tid = threadIdx.x;
    int m0 = blockIdx.x * 128;
#pragma unroll
    for (int i = 0; i < 8; i++) {
        int chunk = i * 256 + tid;
        int row = chunk >> 4, c16 = chunk & 15;
        int sw = ((c16 ^ (row & 7)) << 3);
        int gr = m0 + row;
        int4 va = {0, 0, 0, 0};
        if (gr < M) {
            const float* ap = A + (size_t)gr * 128 + (c16 << 3);
            float4 f0 = *reinterpret_cast<const float4*>(ap);
            float4 f1 = *reinterpret_cast<const float4*>(ap + 4);
            bf16 tmp[8] = {(bf16)f0.x, (bf16)f0.y, (bf16)f0.z, (bf16)f0.w,
                           (bf16)f1.x, (bf16)f1.y, (bf16)f1.z, (bf16)f1.w};
            __builtin_memcpy(&va, tmp, 16);
        }
        *reinterpret_cast<int4*>(&sA[row * 128 + sw]) = va;
        int4 vb = *reinterpret_cast<const int4*>(&BT[(size_t)row * 128 + (c16 << 3)]);
        *reinterpret_cast<int4*>(&sB[row * 128 + sw]) = vb;
    }
    __syncthreads();

    int lane = tid & 63, w = tid >> 6;
    int wm = (w >> 1) * 64, wn = (w & 1) * 64;
    int lr = lane & 15, lk = lane >> 4;
    f32x4 zero = {0.f, 0.f, 0.f, 0.f};
    f32x4 acc[4][4];
#pragma unroll
    for (int mi = 0; mi < 4; mi++)
#pragma unroll
        for (int ni = 0; ni < 4; ni++) acc[mi][ni] = zero;

#pragma unroll
    for (int kk = 0; kk < 4; kk++) {
        int c = (kk << 2) + lk;
        bf16x8 af[4], bfr[4];
#pragma unroll
        for (int mi = 0; mi < 4; mi++) {
            int r = wm + mi * 16 + lr;
            af[mi] = *reinterpret_cast<const bf16x8*>(&sA[r * 128 + ((c ^ (r & 7)) << 3)]);
        }
#pragma unroll
        for (int ni = 0; ni < 4; ni++) {
            int r = wn + ni * 16 + lr;
            bfr[ni] = *reinterpret_cast<const bf16x8*>(&sB[r * 128 + ((c ^ (r & 7)) << 3)]);
        }
#pragma unroll
        for (int mi = 0; mi < 4; mi++)
#pragma unroll
            for (int ni = 0; ni < 4; ni++)
                acc[mi][ni] = __builtin_amdgcn_mfma_f32_16x16x32_bf16(af[mi], bfr[ni], acc[mi][ni], 0, 0, 0);
    }

#pragma unroll
    for (int ni = 0; ni < 4; ni++) {
        int col = wn + ni * 16 + lr;
        float bia = bias[col];
#pragma unroll
        for (int mi = 0; mi < 4; mi++) {
#pragma unroll
            for (int j = 0; j < 4; j++) {
                int row = m0 + wm + mi * 16 + lk * 4 + j;
                if (row < M) C[(size_t)row * 128 + col] = (bf16)(acc[mi][ni][j] + bia);
            }
        }
    }
}

// ---- aggregation (r11): register run-accumulate + last-wins LDS store;
// csr sorted by seg = dst*R + etype so etype runs are contiguous per node.
// G stores NON-TEMPORAL (keeps h L3-resident).
__global__ __launch_bounds__(128) void k_agg2(const bf16* __restrict__ h, const int* __restrict__ row_off,
                                              const int* __restrict__ csr, bf16* __restrict__ G, int N, int R) {
    __shared__ float acc[2][8 * 128];
    int wi = threadIdx.x >> 6;
    int n = blockIdx.x * 2 + wi;
    if (n >= N) return;
    int lane = threadIdx.x & 63;
    int c0 = lane * 2;
    float* a = acc[wi];
#pragma unroll
    for (int i = 0; i < 16; i++) a[i * 64 + lane] = 0.f;
    int beg = row_off[n * R], end = row_off[n * R + R];
    int cur = -1;
    float a0 = 0.f, a1 = 0.f;
    int i = beg;
    for (; i + 4 <= end; i += 4) {
        int p0 = csr[i], p1 = csr[i + 1], p2 = csr[i + 2], p3 = csr[i + 3];
        uint32_t v0 = *reinterpret_cast<const uint32_t*>(&h[(size_t)(p0 & 0xffff) * 128 + c0]);
        uint32_t v1 = *reinterpret_cast<const uint32_t*>(&h[(size_t)(p1 & 0xffff) * 128 + c0]);
        uint32_t v2 = *reinterpret_cast<const uint32_t*>(&h[(size_t)(p2 & 0xffff) * 128 + c0]);
        uint32_t v3 = *reinterpret_cast<const uint32_t*>(&h[(size_t)(p3 & 0xffff) * 128 + c0]);
        {
            int r = p0 >> 16; bool s = (r == cur);
            a0 = (s ? a0 : 0.f) + bfbits2f(v0 & 0xffffu);
            a1 = (s ? a1 : 0.f) + bfbits2f(v0 >> 16);
            cur = r;
            float2 st = {a0, a1};
            *reinterpret_cast<float2*>(&a[r * 128 + c0]) = st;
        }
        {
            int r = p1 >> 16; bool s = (r == cur);
            a0 = (s ? a0 : 0.f) + bfbits2f(v1 & 0xffffu);
            a1 = (s ? a1 : 0.f) + bfbits2f(v1 >> 16);
            cur = r;
            float2 st = {a0, a1};
            *reinterpret_cast<float2*>(&a[r * 128 + c0]) = st;
        }
        {
            int r = p2 >> 16; bool s = (r == cur);
            a0 = (s ? a0 : 0.f) + bfbits2f(v2 & 0xffffu);
            a1 = (s ? a1 : 0.f) + bfbits2f(v2 >> 16);
            cur = r;
            float2 st = {a0, a1};
            *reinterpret_cast<float2*>(&a[r * 128 + c0]) = st;
        }
        {
            int r = p3 >> 16; bool s = (r == cur);
            a0 = (s ? a0 : 0.f) + bfbits2f(v3 & 0xffffu);
            a1 = (s ? a1 : 0.f) + bfbits2f(v3 >> 16);
            cur = r;
            float2 st = {a0, a1};
            *reinterpret_cast<float2*>(&a[r * 128 + c0]) = st;
        }
    }
    for (; i < end; i++) {
        int p = csr[i];
        uint32_t v = *reinterpret_cast<const uint32_t*>(&h[(size_t)(p & 0xffff) * 128 + c0]);
        int r = p >> 16; bool s = (r == cur);
        a0 = (s ? a0 : 0.f) + bfbits2f(v & 0xffffu);
        a1 = (s ? a1 : 0.f) + bfbits2f(v >> 16);
        cur = r;
        float2 st = {a0, a1};
        *reinterpret_cast<float2*>(&a[r * 128 + c0]) = st;
    }
    size_t gbase = (size_t)n * 1024 + c0;
#pragma unroll
    for (int r = 0; r < 8; r++) {
        __builtin_nontemporal_store(pack2bf(a[r * 128 + c0], a[r * 128 + c0 + 1]),
                                    reinterpret_cast<uint32_t*>(&G[gbase + r * 128]));
    }
}

// ---- GEMM2 v4: conv = [G | h] * Wcat + bias_c, f32 out, + fused BN-stats.
// r11 model: staged bytes/time constant at ~4.7-4.9 TB/s across r5/r10 regardless
// of pipeline depth / occupancy -> per-CU in-flight-line cap on the VMEM path
// (rate = Q*line/latency; m97 sustains 3x with L2-resident data). Lever: take
// B (WcatT2, 295KB L2-hot = HALF the staged bytes) OUT of the gload_lds path:
// delete sB, read B-fragments directly from L2 per MFMA (register-read pattern,
// bit-identical to the staged+swizzled read). A-staging (the G stream) kept.
// LDS 66->33KB.
__global__ __launch_bounds__(256) void k_gemm2(const bf16* __restrict__ G, const bf16* __restrict__ hsrc,
                                               const bf16* __restrict__ BT, const float* __restrict__ bias,
                                               float* __restrict__ C, float* __restrict__ stats,
                                               int M, int K) {
    __shared__ bf16 sA[128 * 128];
    __shared__ float csum[128], csum2[128];
    int tid = threadIdx.x;
    if (tid < 128) { csum[tid] = 0.f; csum2[tid] = 0.f; }
    int m0 = blockIdx.x * 128;
    int lane = tid & 63, w = tid >> 6;
    int wm = (w >> 1) * 64, wn = (w & 1) * 64;
    int lr = lane & 15, lk = lane >> 4;
    int l4 = lane >> 4, c16 = lane & 15;
    f32x4 zero = {0.f, 0.f, 0.f, 0.f};
    f32x4 acc[4][4];
#pragma unroll
    for (int mi = 0; mi < 4; mi++)
#pragma unroll
        for (int ni = 0; ni < 4; ni++) acc[mi][ni] = zero;

    int KT = K >> 7;          // 9
    size_t ldg = (size_t)(K - 128);  // 1024 (G row stride)
    for (int kt = 0; kt < KT; kt++) {
        bool lastt = (kt == KT - 1);
        const bf16* Abase = lastt ? hsrc : G;
        size_t ldA = lastt ? 128 : ldg;
        int ka = lastt ? 0 : (kt << 7);
        int k0 = kt << 7;
#pragma unroll
        for (int i = 0; i < 8; i++) {
            int row = i * 16 + (w << 2) + l4;
            int cs = (c16 ^ (row & 7)) << 3;
            int gr = m0 + row;
            gr = gr < M ? gr : M - 1;
            gload_lds16(Abase + (size_t)gr * ldA + ka + cs, &sA[(i * 256 + (w << 6)) * 8]);
        }
        asm volatile("s_waitcnt vmcnt(0)" ::: "memory");
        __syncthreads();

#pragma unroll
        for (int kk = 0; kk < 4; kk++) {
            int c = (kk << 2) + lk;
            bf16x8 af[4], bfr[4];
#pragma unroll
            for (int mi = 0; mi < 4; mi++) {
                int r = wm + mi * 16 + lr;
                af[mi] = *reinterpret_cast<const bf16x8*>(&sA[r * 128 + ((c ^ (r & 7)) << 3)]);
            }
#pragma unroll
            for (int ni = 0; ni < 4; ni++) {
                int o = wn + ni * 16 + lr;
                bfr[ni] = *reinterpret_cast<const bf16x8*>(&BT[(size_t)o * K + k0 + (c << 3)]);
            }
#pragma unroll
            for (int mi = 0; mi < 4; mi++)
#pragma unroll
                for (int ni = 0; ni < 4; ni++)
                    acc[mi][ni] = __builtin_amdgcn_mfma_f32_16x16x32_bf16(af[mi], bfr[ni], acc[mi][ni], 0, 0, 0);
        }
        __syncthreads();  // sA reads done before next stage overwrites
    }

    float ls[4], ls2[4];
#pragma unroll
    for (int ni = 0; ni < 4; ni++) { ls[ni] = 0.f; ls2[ni] = 0.f; }
#pragma unroll
    for (int ni = 0; ni < 4; ni++) {
        int col = wn + ni * 16 + lr;
        float bia = bias[col];
#pragma unroll
        for (int mi = 0; mi < 4; mi++) {
#pragma unroll
            for (int j = 0; j < 4; j++) {
                int row = m0 + wm + mi * 16 + lk * 4 + j;
                if (row < M) {
                    float val = acc[mi][ni][j] + bia;
                    C[(size_t)row * 128 + col] = val;
                    ls[ni] += val;
                    ls2[ni] += val * val;
                }
            }
        }
    }
#pragma unroll
    for (int ni = 0; ni < 4; ni++) {
        float s = ls[ni], s2 = ls2[ni];
        s += __shfl_xor(s, 16); s += __shfl_xor(s, 32);
        s2 += __shfl_xor(s2, 16); s2 += __shfl_xor(s2, 32);
        if (lk == 0) {
            int col = wn + ni * 16 + lr;
            atomicAdd(&csum[col], s);
            atomicAdd(&csum2[col], s2);
        }
    }
    __syncthreads();
    if (tid < 128) {
        atomicAdd(&stats[tid], csum[tid]);
        atomicAdd(&stats[128 + tid], csum2[tid]);
    }
}

// ---- BN + ReLU + cast to bf16 (layer 1); BN coeffs computed inline from
// stats (k_bnfin eliminated -> 2 fewer serializing 1-block dispatches).
__global__ void k_bnrelu(const float* __restrict__ conv, const float* __restrict__ stats,
                         const float* __restrict__ gamma, const float* __restrict__ beta,
                         bf16* __restrict__ h, int N, float invN) {
    int total = N * 32;
    for (int i = blockIdx.x * blockDim.x + threadIdx.x; i < total; i += gridDim.x * blockDim.x) {
        int c4 = (i & 31) << 2;
        float4 v = *reinterpret_cast<const float4*>(&conv[(size_t)i * 4]);
        const float* vv = &v.x;
        uint64_t pk = 0;
#pragma unroll
        for (int j = 0; j < 4; j++) {
            int c = c4 + j;
            float mu = stats[c] * invN;
            float var = stats[128 + c] * invN - mu * mu;
            float sc = gamma[c] * rsqrtf(var + 1e-5f);
            float sh = beta[c] - mu * sc;
            float val = fmaxf(vv[j] * sc + sh, 0.f);
            unsigned short us = __builtin_bit_cast(unsigned short, (bf16)val);
            pk |= (uint64_t)us << (16 * j);
        }
        *reinterpret_cast<uint64_t*>(&h[(size_t)i * 4]) = pk;
    }
}

// ---- layer 2: out[n] = sigmoid(relu(bn(conv[n])) . q + c); BN inline ----
__global__ __launch_bounds__(256) void k_bnout(const float* __restrict__ conv, const float* __restrict__ stats,
                                               const float* __restrict__ gamma, const float* __restrict__ beta,
                                               const float* __restrict__ qc, float* __restrict__ out,
                                               int N, float invN) {
    int wi = threadIdx.x >> 6;
    int n = blockIdx.x * 4 + wi;
    if (n >= N) return;
    int lane = threadIdx.x & 63;
    int c0 = lane * 2;
    float mu0 = stats[c0] * invN;
    float var0 = stats[128 + c0] * invN - mu0 * mu0;
    float sc0 = gamma[c0] * rsqrtf(var0 + 1e-5f);
    float sh0 = beta[c0] - mu0 * sc0;
    float mu1 = stats[c0 + 1] * invN;
    float var1 = stats[128 + c0 + 1] * invN - mu1 * mu1;
    float sc1 = gamma[c0 + 1] * rsqrtf(var1 + 1e-5f);
    float sh1 = beta[c0 + 1] - mu1 * sc1;
    float2 v = *reinterpret_cast<const float2*>(&conv[(size_t)n * 128 + c0]);
    float v0 = fmaxf(v.x * sc0 + sh0, 0.f);
    float v1 = fmaxf(v.y * sc1 + sh1, 0.f);
    float s = v0 * qc[c0] + v1 * qc[c0 + 1];
#pragma unroll
    for (int d = 1; d < 64; d <<= 1) s += __shfl_xor(s, d);
    if (lane == 0) out[n] = 1.f / (1.f + expf(-(s + qc[128])));
}

extern "C" void kernel_launch(void* const* d_in, const int* in_sizes, int n_in,
                              void* d_out, int out_size, void* d_ws, size_t ws_size,
                              hipStream_t stream) {
    const float* x      = (const float*)d_in[0];
    const int*   ei     = (const int*)d_in[1];
    const int*   etype  = (const int*)d_in[2];
    const float* W1     = (const float*)d_in[3];
    const float* b1     = (const float*)d_in[4];
    const float* weight = (const float*)d_in[5];
    const float* root   = (const float*)d_in[6];
    const float* bias_c = (const float*)d_in[7];
    const float* gamma  = (const float*)d_in[8];
    const float* beta   = (const float*)d_in[9];
    const float* W2     = (const float*)d_in[10];
    const float* b2     = (const float*)d_in[11];
    const float* Wo     = (const float*)d_in[12];
    const float* bo     = (const float*)d_in[13];
    float* out = (float*)d_out;

    int H = in_sizes[4];            // 128
    int F = in_sizes[3] / H;        // 128
    int N = in_sizes[0] / F;        // 50000
    int E = in_sizes[2];            // 800000
    int R = in_sizes[5] / (H * H);  // 8
    int ldt = (R + 1) * H;          // 1152
    int M = N * R;                  // 400000 segments (seg = dst*R + etype)

    const int* srcv = ei;
    const int* dstv = ei + E;

    char* p = (char*)d_ws;
    auto alloc = [&](size_t bytes) -> char* {
        char* r = p;
        p += (bytes + 255) & ~(size_t)255;
        return r;
    };
    bf16*  G       = (bf16*)alloc((size_t)N * (R * H) * 2);
    bf16*  h       = (bf16*)alloc((size_t)N * H * 2);
    float* conv    = (float*)alloc((size_t)N * H * 4);
    bf16*  WcatT2  = (bf16*)alloc((size_t)ldt * H * 2);
    bf16*  W1T     = (bf16*)alloc((size_t)F * H * 2);
    float* qc      = (float*)alloc(129 * 4);
    int*   cnt     = (int*)alloc((size_t)M * 4);
    int*   row_off = (int*)alloc((size_t)(M + 1) * 4);
    int*   cursor  = (int*)alloc((size_t)M * 4);
    int*   csr     = (int*)alloc((size_t)E * 4);
    float* stats   = (float*)alloc(512 * 4);   // two 256-float halves (layer 0 / layer 1)
    int*   bsum    = (int*)alloc(2048 * 4);
    if ((size_t)(p - (char*)d_ws) > ws_size) return;

    int nb = (M + 255) / 256;  // 1563 <= 2048
    int pbase = (M + 7) / 8;   // seg-partition width for XCD-local csr fill

    hipMemsetAsync(cnt, 0, (size_t)M * 4, stream);
    hipMemsetAsync(stats, 0, 512 * 4, stream);
    k_prep<<<256, 256, 0, stream>>>(W1, weight, root, W2, b2, Wo, bo, W1T, WcatT2, qc, R, ldt);
    k_hist<<<1024, 256, 0, stream>>>(dstv, etype, cnt, E, R);
    k_scan_blk<<<nb, 256, 0, stream>>>(cnt, bsum, M);
    k_scan_top<<<1, 256, 0, stream>>>(bsum, nb);
    k_scan_apply<<<nb, 256, 0, stream>>>(cnt, bsum, row_off, cursor, M);
    k_fill<<<1024, 256, 0, stream>>>(srcv, dstv, etype, cursor, csr, E, R, pbase);

    int mb = (N + 127) / 128;
    k_gemm0<<<mb, 256, 0, stream>>>(x, W1T, b1, h, N);

    float invN = 1.f / (float)N;
    for (int l = 0; l < 2; l++) {
        float* statsl = stats + l * 256;
        k_agg2<<<(N + 1) / 2, 128, 0, stream>>>(h, row_off, csr, G, N, R);
        k_gemm2<<<mb, 256, 0, stream>>>(G, h, WcatT2, bias_c, conv, statsl, N, ldt);
        if (l == 0)
            k_bnrelu<<<2048, 256, 0, stream>>>(conv, statsl, gamma, beta, h, N, invN);
        else
            k_bnout<<<(N + 3) / 4, 256, 0, stream>>>(conv, statsl, gamma, beta, qc, out, N, invN);
    }
}

// Round 13
// 305.668 us; speedup vs baseline: 1.1231x; 1.1231x over previous
//
#include <hip/hip_runtime.h>
#include <stdint.h>

typedef __bf16 bf16;
typedef __bf16 bf16x8 __attribute__((ext_vector_type(8)));
typedef float f32x4 __attribute__((ext_vector_type(4)));

__device__ __forceinline__ float bfbits2f(uint32_t lo16) {
    uint32_t b = lo16 << 16;
    float f;
    __builtin_memcpy(&f, &b, 4);
    return f;
}

__device__ __forceinline__ uint32_t pack2bf(float a, float b) {
    uint32_t lo = __builtin_bit_cast(unsigned short, (bf16)a);
    uint32_t hi = __builtin_bit_cast(unsigned short, (bf16)b);
    return lo | (hi << 16);
}

__device__ __forceinline__ void gload_lds16(const void* g, void* l) {
    __builtin_amdgcn_global_load_lds((const __attribute__((address_space(1))) void*)g,
                                     (__attribute__((address_space(3))) void*)l, 16, 0, 0);
}

// ---- prep: W1T[h][f]=W1[f][h];  WcatT2[o][r*128+c]=weight[r][c][o],
// WcatT2[o][R*128+c]=root[c][o];  tail computes qc:
// qc[i]=sum_j W2[i][j]*Wo[j], qc[128]=b2.Wo+bo
__global__ void k_prep(const float* __restrict__ W1, const float* __restrict__ weight,
                       const float* __restrict__ root, const float* __restrict__ W2,
                       const float* __restrict__ b2, const float* __restrict__ Wo,
                       const float* __restrict__ bo, bf16* __restrict__ W1T,
                       bf16* __restrict__ WcatT2, float* __restrict__ qc, int R, int ldt) {
    int total = 16384 * (R + 2);
    for (int i = blockIdx.x * blockDim.x + threadIdx.x; i < total + 129; i += gridDim.x * blockDim.x) {
        if (i < 16384) {
            int f = i >> 7, h = i & 127;
            W1T[h * 128 + f] = (bf16)W1[f * 128 + h];
        } else if (i < total) {
            int j = i - 16384;
            int r = j >> 14, rem = j & 16383, c = rem >> 7, o = rem & 127;
            float v = (r < R) ? weight[(size_t)(r * 128 + c) * 128 + o] : root[c * 128 + o];
            WcatT2[(size_t)o * ldt + r * 128 + c] = (bf16)v;
        } else {
            int t = i - total;
            if (t < 128) {
                float s = 0.f;
                for (int j = 0; j < 128; j++) s += W2[t * 128 + j] * Wo[j];
                qc[t] = s;
            } else {
                float c = bo[0];
                for (int j = 0; j < 128; j++) c += b2[j] * Wo[j];
                qc[128] = c;
            }
        }
    }
}

// ---- CSR build over segments seg = dst*R + etype (dst-major: node's edges
// contiguous AND grouped by etype -> agg2 run-accumulation). k_hist also
// precomputes seg[] and pay[]=(etype<<16)|src so k_fill's 8 partition-peers
// re-read 2 arrays instead of 3 (r12: fill re-read was 76.8MB; now 51.2MB).
__global__ void k_hist(const int* __restrict__ src, const int* __restrict__ dst,
                       const int* __restrict__ etype, int* __restrict__ cnt,
                       int* __restrict__ seg, int* __restrict__ pay, int E, int R) {
    for (int e = blockIdx.x * blockDim.x + threadIdx.x; e < E; e += gridDim.x * blockDim.x) {
        int et = etype[e];
        int s = dst[e] * R + et;
        seg[e] = s;
        pay[e] = (et << 16) | src[e];
        atomicAdd(&cnt[s], 1);
    }
}

__global__ __launch_bounds__(256) void k_scan_blk(const int* __restrict__ cnt, int* __restrict__ bsum, int M) {
    int i = blockIdx.x * 256 + threadIdx.x;
    int v = (i < M) ? cnt[i] : 0;
#pragma unroll
    for (int d = 1; d < 64; d <<= 1) v += __shfl_xor(v, d);
    __shared__ int ws[4];
    if ((threadIdx.x & 63) == 0) ws[threadIdx.x >> 6] = v;
    __syncthreads();
    if (threadIdx.x == 0) bsum[blockIdx.x] = ws[0] + ws[1] + ws[2] + ws[3];
}

// looped single-block exclusive scan over nb block sums (nb up to 2048)
__global__ __launch_bounds__(256) void k_scan_top(int* __restrict__ bsum, int nb) {
    __shared__ int s[256];
    __shared__ int carry;
    int t = threadIdx.x;
    if (t == 0) carry = 0;
    __syncthreads();
    for (int base = 0; base < nb; base += 256) {
        int i = base + t;
        int v = (i < nb) ? bsum[i] : 0;
        s[t] = v;
        __syncthreads();
#pragma unroll
        for (int d = 1; d < 256; d <<= 1) {
            int u = (t >= d) ? s[t - d] : 0;
            __syncthreads();
            s[t] += u;
            __syncthreads();
        }
        int excl = carry + s[t] - v;
        int tot = s[255];
        __syncthreads();
        if (i < nb) bsum[i] = excl;
        if (t == 0) carry += tot;
        __syncthreads();
    }
}

__global__ __launch_bounds__(256) void k_scan_apply(const int* __restrict__ cnt, const int* __restrict__ bsum,
                                                    int* __restrict__ row_off, int* __restrict__ cursor, int M) {
    int b = blockIdx.x, t = threadIdx.x;
    int i = b * 256 + t;
    int v = (i < M) ? cnt[i] : 0;
    int lane = t & 63, wid = t >> 6;
    int incl = v;
#pragma unroll
    for (int d = 1; d < 64; d <<= 1) {
        int u = __shfl_up(incl, d);
        if (lane >= d) incl += u;
    }
    __shared__ int ws[4];
    if (lane == 63) ws[wid] = incl;
    __syncthreads();
    int woff = 0;
    for (int wj = 0; wj < 4; wj++)
        if (wj < wid) woff += ws[wj];
    int excl = bsum[b] + woff + incl - v;
    if (i < M) {
        row_off[i] = excl;
        cursor[i] = excl;
        if (i == M - 1) row_off[M] = excl + v;
    }
}

// XCD-partitioned CSR fill on seg ranges; reads precomputed seg/pay only.
__global__ void k_fill(const int* __restrict__ seg, const int* __restrict__ pay,
                       int* __restrict__ cursor, int* __restrict__ csr, int E, int pbase) {
    int p = blockIdx.x & 7;
    int bg = blockIdx.x >> 3;
    int nchunk = gridDim.x >> 3;
    int chunk = (E + nchunk - 1) / nchunk;
    int beg = bg * chunk, end = min(beg + chunk, E);
    int lo = p * pbase, hi = lo + pbase;
    for (int e = beg + (int)threadIdx.x; e < end; e += blockDim.x) {
        int s = seg[e];
        if (s >= lo && s < hi) {
            int pos = atomicAdd(&cursor[s], 1);
            csr[pos] = pay[e];
        }
    }
}

// ---- GEMM (layer 0): C[M x 128] = A_f32[M x 128] * B[128 x 128] (+bias), bf16 out
__global__ __launch_bounds__(256) void k_gemm0(const float* __restrict__ A, const bf16* __restrict__ BT,
                                               const float* __restrict__ bias, bf16* __restrict__ C, int M) {
    __shared__ bf16 sA[128 * 128];
    __shared__ bf16 sB[128 * 128];
    int tid = threadIdx.x;
    int m0 = blockIdx.x * 128;
#pragma unroll
    for (int i = 0; i < 8; i++) {
        int chunk = i * 256 + tid;
        int row = chunk >> 4, c16 = chunk & 15;
        int sw = ((c16 ^ (row & 7)) << 3);
        int gr = m0 + row;
        int4 va = {0, 0, 0, 0};
        if (gr < M) {
            const float* ap = A + (size_t)gr * 128 + (c16 << 3);
            float4 f0 = *reinterpret_cast<const float4*>(ap);
            float4 f1 = *reinterpret_cast<const float4*>(ap + 4);
            bf16 tmp[8] = {(bf16)f0.x, (bf16)f0.y, (bf16)f0.z, (bf16)f0.w,
                           (bf16)f1.x, (bf16)f1.y, (bf16)f1.z, (bf16)f1.w};
            __builtin_memcpy(&va, tmp, 16);
        }
        *reinterpret_cast<int4*>(&sA[row * 128 + sw]) = va;
        int4 vb = *reinterpret_cast<const int4*>(&BT[(size_t)row * 128 + (c16 << 3)]);
        *reinterpret_cast<int4*>(&sB[row * 128 + sw]) = vb;
    }
    __syncthreads();

    int lane = tid & 63, w = tid >> 6;
    int wm = (w >> 1) * 64, wn = (w & 1) * 64;
    int lr = lane & 15, lk = lane >> 4;
    f32x4 zero = {0.f, 0.f, 0.f, 0.f};
    f32x4 acc[4][4];
#pragma unroll
    for (int mi = 0; mi < 4; mi++)
#pragma unroll
        for (int ni = 0; ni < 4; ni++) acc[mi][ni] = zero;

#pragma unroll
    for (int kk = 0; kk < 4; kk++) {
        int c = (kk << 2) + lk;
        bf16x8 af[4], bfr[4];
#pragma unroll
        for (int mi = 0; mi < 4; mi++) {
            int r = wm + mi * 16 + lr;
            af[mi] = *reinterpret_cast<const bf16x8*>(&sA[r * 128 + ((c ^ (r & 7)) << 3)]);
        }
#pragma unroll
        for (int ni = 0; ni < 4; ni++) {
            int r = wn + ni * 16 + lr;
            bfr[ni] = *reinterpret_cast<const bf16x8*>(&sB[r * 128 + ((c ^ (r & 7)) << 3)]);
        }
#pragma unroll
        for (int mi = 0; mi < 4; mi++)
#pragma unroll
            for (int ni = 0; ni < 4; ni++)
                acc[mi][ni] = __builtin_amdgcn_mfma_f32_16x16x32_bf16(af[mi], bfr[ni], acc[mi][ni], 0, 0, 0);
    }

#pragma unroll
    for (int ni = 0; ni < 4; ni++) {
        int col = wn + ni * 16 + lr;
        float bia = bias[col];
#pragma unroll
        for (int mi = 0; mi < 4; mi++) {
#pragma unroll
            for (int j = 0; j < 4; j++) {
                int row = m0 + wm + mi * 16 + lk * 4 + j;
                if (row < M) C[(size_t)row * 128 + col] = (bf16)(acc[mi][ni][j] + bia);
            }
        }
    }
}

// ---- aggregation: register run-accumulate + last-wins LDS store; 8-deep
// load batch (was 4; VGPR headroom large, doubles MLP in the latency-bound
// gather). csr sorted by seg = dst*R+etype so etype runs are contiguous per
// node; run state (cur,a0,a1) persists across batches. G stores NON-TEMPORAL
// (keeps h L3-resident).
__global__ __launch_bounds__(128) void k_agg2(const bf16* __restrict__ h, const int* __restrict__ row_off,
                                              const int* __restrict__ csr, bf16* __restrict__ G, int N, int R) {
    __shared__ float acc[2][8 * 128];
    int wi = threadIdx.x >> 6;
    int n = blockIdx.x * 2 + wi;
    if (n >= N) return;
    int lane = threadIdx.x & 63;
    int c0 = lane * 2;
    float* a = acc[wi];
#pragma unroll
    for (int i = 0; i < 16; i++) a[i * 64 + lane] = 0.f;
    int beg = row_off[n * R], end = row_off[n * R + R];
    int cur = -1;
    float a0 = 0.f, a1 = 0.f;
    int i = beg;
    for (; i + 8 <= end; i += 8) {
        int pp[8];
        uint32_t vv[8];
#pragma unroll
        for (int u = 0; u < 8; u++) pp[u] = csr[i + u];
#pragma unroll
        for (int u = 0; u < 8; u++)
            vv[u] = *reinterpret_cast<const uint32_t*>(&h[(size_t)(pp[u] & 0xffff) * 128 + c0]);
#pragma unroll
        for (int u = 0; u < 8; u++) {
            int r = pp[u] >> 16;
            bool s = (r == cur);
            a0 = (s ? a0 : 0.f) + bfbits2f(vv[u] & 0xffffu);
            a1 = (s ? a1 : 0.f) + bfbits2f(vv[u] >> 16);
            cur = r;
            float2 st = {a0, a1};
            *reinterpret_cast<float2*>(&a[r * 128 + c0]) = st;
        }
    }
    for (; i < end; i++) {
        int p = csr[i];
        uint32_t v = *reinterpret_cast<const uint32_t*>(&h[(size_t)(p & 0xffff) * 128 + c0]);
        int r = p >> 16;
        bool s = (r == cur);
        a0 = (s ? a0 : 0.f) + bfbits2f(v & 0xffffu);
        a1 = (s ? a1 : 0.f) + bfbits2f(v >> 16);
        cur = r;
        float2 st = {a0, a1};
        *reinterpret_cast<float2*>(&a[r * 128 + c0]) = st;
    }
    size_t gbase = (size_t)n * 1024 + c0;
#pragma unroll
    for (int r = 0; r < 8; r++) {
        __builtin_nontemporal_store(pack2bf(a[r * 128 + c0], a[r * 128 + c0 + 1]),
                                    reinterpret_cast<uint32_t*>(&G[gbase + r * 128]));
    }
}

// ---- GEMM2 (measured-best config, 6 variants tested r5-r12): conv = [G | h]
// * Wcat + bias_c, f32 out, + fused BN-stats. 128-tile, A+B staged via
// gload_lds, vmcnt(0) drain per K-tile. r12 (no-sB) proved B-through-LDS is
// the cheap path (per-MFMA L2 B-reads = 8x B traffic, +18us).
__global__ __launch_bounds__(256) void k_gemm2(const bf16* __restrict__ G, const bf16* __restrict__ hsrc,
                                               const bf16* __restrict__ BT, const float* __restrict__ bias,
                                               float* __restrict__ C, float* __restrict__ stats,
                                               int M, int K) {
    __shared__ bf16 sA[128 * 128];
    __shared__ bf16 sB[128 * 128];
    __shared__ float csum[128], csum2[128];
    int tid = threadIdx.x;
    if (tid < 128) { csum[tid] = 0.f; csum2[tid] = 0.f; }
    int m0 = blockIdx.x * 128;
    int lane = tid & 63, w = tid >> 6;
    int wm = (w >> 1) * 64, wn = (w & 1) * 64;
    int lr = lane & 15, lk = lane >> 4;
    int l4 = lane >> 4, c16 = lane & 15;
    f32x4 zero = {0.f, 0.f, 0.f, 0.f};
    f32x4 acc[4][4];
#pragma unroll
    for (int mi = 0; mi < 4; mi++)
#pragma unroll
        for (int ni = 0; ni < 4; ni++) acc[mi][ni] = zero;

    int KT = K >> 7;          // 9
    size_t ldg = (size_t)(K - 128);  // 1024 (G row stride)
    for (int kt = 0; kt < KT; kt++) {
        bool lastt = (kt == KT - 1);
        const bf16* Abase = lastt ? hsrc : G;
        size_t ldA = lastt ? 128 : ldg;
        int ka = lastt ? 0 : (kt << 7);
        int k0 = kt << 7;
#pragma unroll
        for (int i = 0; i < 8; i++) {
            int row = i * 16 + (w << 2) + l4;
            int cs = (c16 ^ (row & 7)) << 3;
            int gr = m0 + row;
            gr = gr < M ? gr : M - 1;
            gload_lds16(Abase + (size_t)gr * ldA + ka + cs, &sA[(i * 256 + (w << 6)) * 8]);
            gload_lds16(&BT[(size_t)row * K + k0 + cs], &sB[(i * 256 + (w << 6)) * 8]);
        }
        asm volatile("s_waitcnt vmcnt(0)" ::: "memory");
        __syncthreads();

#pragma unroll
        for (int kk = 0; kk < 4; kk++) {
            int c = (kk << 2) + lk;
            bf16x8 af[4], bfr[4];
#pragma unroll
            for (int mi = 0; mi < 4; mi++) {
                int r = wm + mi * 16 + lr;
                af[mi] = *reinterpret_cast<const bf16x8*>(&sA[r * 128 + ((c ^ (r & 7)) << 3)]);
            }
#pragma unroll
            for (int ni = 0; ni < 4; ni++) {
                int r = wn + ni * 16 + lr;
                bfr[ni] = *reinterpret_cast<const bf16x8*>(&sB[r * 128 + ((c ^ (r & 7)) << 3)]);
            }
#pragma unroll
            for (int mi = 0; mi < 4; mi++)
#pragma unroll
                for (int ni = 0; ni < 4; ni++)
                    acc[mi][ni] = __builtin_amdgcn_mfma_f32_16x16x32_bf16(af[mi], bfr[ni], acc[mi][ni], 0, 0, 0);
        }
        __syncthreads();
    }

    float ls[4], ls2[4];
#pragma unroll
    for (int ni = 0; ni < 4; ni++) { ls[ni] = 0.f; ls2[ni] = 0.f; }
#pragma unroll
    for (int ni = 0; ni < 4; ni++) {
        int col = wn + ni * 16 + lr;
        float bia = bias[col];
#pragma unroll
        for (int mi = 0; mi < 4; mi++) {
#pragma unroll
            for (int j = 0; j < 4; j++) {
                int row = m0 + wm + mi * 16 + lk * 4 + j;
                if (row < M) {
                    float val = acc[mi][ni][j] + bia;
                    C[(size_t)row * 128 + col] = val;
                    ls[ni] += val;
                    ls2[ni] += val * val;
                }
            }
        }
    }
#pragma unroll
    for (int ni = 0; ni < 4; ni++) {
        float s = ls[ni], s2 = ls2[ni];
        s += __shfl_xor(s, 16); s += __shfl_xor(s, 32);
        s2 += __shfl_xor(s2, 16); s2 += __shfl_xor(s2, 32);
        if (lk == 0) {
            int col = wn + ni * 16 + lr;
            atomicAdd(&csum[col], s);
            atomicAdd(&csum2[col], s2);
        }
    }
    __syncthreads();
    if (tid < 128) {
        atomicAdd(&stats[tid], csum[tid]);
        atomicAdd(&stats[128 + tid], csum2[tid]);
    }
}

// ---- BN + ReLU + cast to bf16 (layer 1); BN coeffs computed inline from stats
__global__ void k_bnrelu(const float* __restrict__ conv, const float* __restrict__ stats,
                         const float* __restrict__ gamma, const float* __restrict__ beta,
                         bf16* __restrict__ h, int N, float invN) {
    int total = N * 32;
    for (int i = blockIdx.x * blockDim.x + threadIdx.x; i < total; i += gridDim.x * blockDim.x) {
        int c4 = (i & 31) << 2;
        float4 v = *reinterpret_cast<const float4*>(&conv[(size_t)i * 4]);
        const float* vv = &v.x;
        uint64_t pk = 0;
#pragma unroll
        for (int j = 0; j < 4; j++) {
            int c = c4 + j;
            float mu = stats[c] * invN;
            float var = stats[128 + c] * invN - mu * mu;
            float sc = gamma[c] * rsqrtf(var + 1e-5f);
            float sh = beta[c] - mu * sc;
            float val = fmaxf(vv[j] * sc + sh, 0.f);
            unsigned short us = __builtin_bit_cast(unsigned short, (bf16)val);
            pk |= (uint64_t)us << (16 * j);
        }
        *reinterpret_cast<uint64_t*>(&h[(size_t)i * 4]) = pk;
    }
}

// ---- layer 2: out[n] = sigmoid(relu(bn(conv[n])) . q + c); BN inline ----
__global__ __launch_bounds__(256) void k_bnout(const float* __restrict__ conv, const float* __restrict__ stats,
                                               const float* __restrict__ gamma, const float* __restrict__ beta,
                                               const float* __restrict__ qc, float* __restrict__ out,
                                               int N, float invN) {
    int wi = threadIdx.x >> 6;
    int n = blockIdx.x * 4 + wi;
    if (n >= N) return;
    int lane = threadIdx.x & 63;
    int c0 = lane * 2;
    float mu0 = stats[c0] * invN;
    float var0 = stats[128 + c0] * invN - mu0 * mu0;
    float sc0 = gamma[c0] * rsqrtf(var0 + 1e-5f);
    float sh0 = beta[c0] - mu0 * sc0;
    float mu1 = stats[c0 + 1] * invN;
    float var1 = stats[128 + c0 + 1] * invN - mu1 * mu1;
    float sc1 = gamma[c0 + 1] * rsqrtf(var1 + 1e-5f);
    float sh1 = beta[c0 + 1] - mu1 * sc1;
    float2 v = *reinterpret_cast<const float2*>(&conv[(size_t)n * 128 + c0]);
    float v0 = fmaxf(v.x * sc0 + sh0, 0.f);
    float v1 = fmaxf(v.y * sc1 + sh1, 0.f);
    float s = v0 * qc[c0] + v1 * qc[c0 + 1];
#pragma unroll
    for (int d = 1; d < 64; d <<= 1) s += __shfl_xor(s, d);
    if (lane == 0) out[n] = 1.f / (1.f + expf(-(s + qc[128])));
}

extern "C" void kernel_launch(void* const* d_in, const int* in_sizes, int n_in,
                              void* d_out, int out_size, void* d_ws, size_t ws_size,
                              hipStream_t stream) {
    const float* x      = (const float*)d_in[0];
    const int*   ei     = (const int*)d_in[1];
    const int*   etype  = (const int*)d_in[2];
    const float* W1     = (const float*)d_in[3];
    const float* b1     = (const float*)d_in[4];
    const float* weight = (const float*)d_in[5];
    const float* root   = (const float*)d_in[6];
    const float* bias_c = (const float*)d_in[7];
    const float* gamma  = (const float*)d_in[8];
    const float* beta   = (const float*)d_in[9];
    const float* W2     = (const float*)d_in[10];
    const float* b2     = (const float*)d_in[11];
    const float* Wo     = (const float*)d_in[12];
    const float* bo     = (const float*)d_in[13];
    float* out = (float*)d_out;

    int H = in_sizes[4];            // 128
    int F = in_sizes[3] / H;        // 128
    int N = in_sizes[0] / F;        // 50000
    int E = in_sizes[2];            // 800000
    int R = in_sizes[5] / (H * H);  // 8
    int ldt = (R + 1) * H;          // 1152
    int M = N * R;                  // 400000 segments (seg = dst*R + etype)

    const int* srcv = ei;
    const int* dstv = ei + E;

    char* p = (char*)d_ws;
    auto alloc = [&](size_t bytes) -> char* {
        char* r = p;
        p += (bytes + 255) & ~(size_t)255;
        return r;
    };
    bf16*  G       = (bf16*)alloc((size_t)N * (R * H) * 2);
    bf16*  h       = (bf16*)alloc((size_t)N * H * 2);
    float* conv    = (float*)alloc((size_t)N * H * 4);
    bf16*  WcatT2  = (bf16*)alloc((size_t)ldt * H * 2);
    bf16*  W1T     = (bf16*)alloc((size_t)F * H * 2);
    float* qc      = (float*)alloc(129 * 4);
    int*   cnt     = (int*)alloc((size_t)M * 4);
    int*   row_off = (int*)alloc((size_t)(M + 1) * 4);
    int*   cursor  = (int*)alloc((size_t)M * 4);
    int*   csr     = (int*)alloc((size_t)E * 4);
    int*   seg     = (int*)alloc((size_t)E * 4);
    int*   pay     = (int*)alloc((size_t)E * 4);
    float* stats   = (float*)alloc(512 * 4);   // two 256-float halves (layer 0 / layer 1)
    int*   bsum    = (int*)alloc(2048 * 4);
    if ((size_t)(p - (char*)d_ws) > ws_size) return;

    int nb = (M + 255) / 256;  // 1563 <= 2048
    int pbase = (M + 7) / 8;   // seg-partition width for XCD-local csr fill

    hipMemsetAsync(cnt, 0, (size_t)M * 4, stream);
    hipMemsetAsync(stats, 0, 512 * 4, stream);
    k_prep<<<256, 256, 0, stream>>>(W1, weight, root, W2, b2, Wo, bo, W1T, WcatT2, qc, R, ldt);
    k_hist<<<1024, 256, 0, stream>>>(srcv, dstv, etype, cnt, seg, pay, E, R);
    k_scan_blk<<<nb, 256, 0, stream>>>(cnt, bsum, M);
    k_scan_top<<<1, 256, 0, stream>>>(bsum, nb);
    k_scan_apply<<<nb, 256, 0, stream>>>(cnt, bsum, row_off, cursor, M);
    k_fill<<<1024, 256, 0, stream>>>(seg, pay, cursor, csr, E, pbase);

    int mb = (N + 127) / 128;
    k_gemm0<<<mb, 256, 0, stream>>>(x, W1T, b1, h, N);

    float invN = 1.f / (float)N;
    for (int l = 0; l < 2; l++) {
        float* statsl = stats + l * 256;
        k_agg2<<<(N + 1) / 2, 128, 0, stream>>>(h, row_off, csr, G, N, R);
        k_gemm2<<<mb, 256, 0, stream>>>(G, h, WcatT2, bias_c, conv, statsl, N, ldt);
        if (l == 0)
            k_bnrelu<<<2048, 256, 0, stream>>>(conv, statsl, gamma, beta, h, N, invN);
        else
            k_bnout<<<(N + 3) / 4, 256, 0, stream>>>(conv, statsl, gamma, beta, qc, out, N, invN);
    }
}